// Round 2
// baseline (328.450 us; speedup 1.0000x reference)
//
#include <hip/hip_runtime.h>
#include <hip/hip_bf16.h>

// ProjectionPursuitProbe: h' = scale * (h - P G^{-1} P^T h), G = P^T P
// B=8, S=4096, F=1024, R=64. Rows N = 32768.
//
// R2 structure: no LDS staging of H. MFMA A-fragments (A[m=lane&15][k=quad*8+j])
// are 8 contiguous row elements -> load straight from global, cvt to bf16 in regs.
// B-fragments come from small packed bf16 arrays (Ptb/Pb/Wb), L1/L2-resident.
// Only 2 __syncthreads per block (phase transitions). 35 KB LDS -> 4 blocks/CU.

typedef __attribute__((ext_vector_type(8))) short bf16x8;
typedef __attribute__((ext_vector_type(4))) float f32x4;

#define MFMA_B16(a, b, c) __builtin_amdgcn_mfma_f32_16x16x32_bf16((a), (b), (c), 0, 0, 0)

__device__ __forceinline__ unsigned short bf16bits(float x) {
  union { float f; unsigned u; } v; v.f = x;
  return (unsigned short)((v.u + 0x7fffu + ((v.u >> 16) & 1u)) >> 16);  // RNE
}

__device__ __forceinline__ bf16x8 packbf8(f32x4 v0, f32x4 v1) {
  union { bf16x8 v; __hip_bfloat162 h[4]; } u;
  u.h[0] = __float22bfloat162_rn(make_float2(v0[0], v0[1]));
  u.h[1] = __float22bfloat162_rn(make_float2(v0[2], v0[3]));
  u.h[2] = __float22bfloat162_rn(make_float2(v1[0], v1[1]));
  u.h[3] = __float22bfloat162_rn(make_float2(v1[2], v1[3]));
  return u.v;
}

__device__ __forceinline__ bf16x8 cvt8(const float* p) {  // 8 LDS floats -> bf16x8
  return packbf8(*(const f32x4*)p, *(const f32x4*)(p + 4));
}

// ---------------- K1: gram partials + pack P to bf16 (Ptb r-major, Pb f-major) ----------
__global__ void pp_prep(const float* __restrict__ P, float* __restrict__ partial,
                        unsigned short* __restrict__ Ptb, unsigned short* __restrict__ Pb) {
  __shared__ float Pl[64][68];
  const int tid = threadIdx.x, ch = blockIdx.x;
  #pragma unroll
  for (int u = 0; u < 4; ++u) {
    const int f = tid >> 2, r = (tid & 3) * 16 + 4 * u;
    *(f32x4*)&Pl[f][r] = *(const f32x4*)(P + (size_t)(ch * 64 + f) * 64 + r);
  }
  __syncthreads();
  // gram partial: partial[ch] = P_chunk^T @ P_chunk (64x64)
  const int a0 = (tid >> 4) * 4, b0 = (tid & 15) * 4;
  f32x4 acc[4];
  #pragma unroll
  for (int i = 0; i < 4; ++i) acc[i] = (f32x4){0.f, 0.f, 0.f, 0.f};
  for (int k = 0; k < 64; ++k) {
    f32x4 av = *(const f32x4*)&Pl[k][a0];
    f32x4 bv = *(const f32x4*)&Pl[k][b0];
    #pragma unroll
    for (int i = 0; i < 4; ++i) acc[i] += av[i] * bv;
  }
  #pragma unroll
  for (int i = 0; i < 4; ++i)
    *(f32x4*)(partial + (size_t)ch * 4096 + (size_t)(a0 + i) * 64 + b0) = acc[i];
  // pack: thread handles row f (global gf), 16 r-columns starting at c0
  const int f = tid >> 2, c0 = (tid & 3) * 16;
  const int gf = ch * 64 + f;
  unsigned short b16[16];
  #pragma unroll
  for (int u = 0; u < 16; ++u) b16[u] = bf16bits(Pl[f][c0 + u]);
  #pragma unroll
  for (int u = 0; u < 16; ++u) Ptb[(size_t)(c0 + u) * 1024 + gf] = b16[u];
  #pragma unroll
  for (int w = 0; w < 4; ++w) {
    unsigned long long q = (unsigned long long)b16[4 * w] |
                           ((unsigned long long)b16[4 * w + 1] << 16) |
                           ((unsigned long long)b16[4 * w + 2] << 32) |
                           ((unsigned long long)b16[4 * w + 3] << 48);
    *(unsigned long long*)(Pb + (size_t)gf * 64 + c0 + 4 * w) = q;
  }
}

// ---------------- K2: G = sum partials; Wb = bf16(G^{-1}) via Gauss-Jordan (SPD) ----------
__global__ void pp_invert(const float* __restrict__ partial, unsigned short* __restrict__ Wb) {
  __shared__ float A[64][68];
  const int tid = threadIdx.x;
  const int i = tid >> 2, q16 = (tid & 3) * 16;
  #pragma unroll
  for (int u = 0; u < 4; ++u) {
    f32x4 s = (f32x4){0.f, 0.f, 0.f, 0.f};
    const int off = i * 64 + q16 + 4 * u;
    for (int p = 0; p < 16; ++p) s += *(const f32x4*)(partial + (size_t)p * 4096 + off);
    *(f32x4*)&A[i][q16 + 4 * u] = s;
  }
  __syncthreads();
  for (int k = 0; k < 64; ++k) {
    const float d = 1.0f / A[k][k];
    const float f = A[i][k];
    f32x4 prs[4], cur[4];
    #pragma unroll
    for (int u = 0; u < 4; ++u) {
      prs[u] = *(const f32x4*)&A[k][q16 + 4 * u];
      cur[u] = *(const f32x4*)&A[i][q16 + 4 * u];
    }
    __syncthreads();  // all reads done before any writes
    const int kl = k - q16;
    #pragma unroll
    for (int u = 0; u < 4; ++u) {
      f32x4 pv = prs[u] * d;
      if (kl >= u * 4 && kl < u * 4 + 4) { pv[kl - u * 4] = d; cur[u][kl - u * 4] = 0.f; }
      f32x4 res = (i == k) ? pv : (cur[u] - f * pv);
      *(f32x4*)&A[i][q16 + 4 * u] = res;
    }
    __syncthreads();
  }
  #pragma unroll
  for (int u = 0; u < 4; ++u) {
    #pragma unroll
    for (int j = 0; j < 4; ++j) Wb[(size_t)i * 64 + q16 + 4 * u + j] = bf16bits(A[i][q16 + 4 * u + j]);
  }
}

// ---------------- K3: fused main, 16 rows/wave, 64 rows/block, no K-loop barriers --------
__global__ __launch_bounds__(256, 4) void pp_main(
    const float* __restrict__ H, const unsigned short* __restrict__ Ptb,
    const unsigned short* __restrict__ Pb, const unsigned short* __restrict__ Wb,
    float* __restrict__ out) {
  __shared__ float Yl[4][16][68];  // per-wave Y slice (fp32)
  __shared__ float Cl[4][16][68];  // per-wave C slice (fp32)

  const int tid = threadIdx.x, wid = tid >> 6, lane = tid & 63;
  const int c16 = lane & 15, quad = lane >> 4;
  const long rowbase = (long)blockIdx.x * 64 + wid * 16;  // wave's first row
  const float* hrow = H + (rowbase + c16) * 1024 + quad * 8;

  // ---- phase 1: Y = H @ P (K=1024), A=H direct from global, B=Ptb; + row sum-sq ----
  f32x4 accY[4];
  #pragma unroll
  for (int t = 0; t < 4; ++t) accY[t] = (f32x4){0.f, 0.f, 0.f, 0.f};
  float sq = 0.f;
  const unsigned short* pB = Ptb + (size_t)c16 * 1024 + quad * 8;
  #pragma unroll 4
  for (int kk = 0; kk < 32; ++kk) {
    f32x4 v0 = *(const f32x4*)(hrow + kk * 32);
    f32x4 v1 = *(const f32x4*)(hrow + kk * 32 + 4);
    sq += v0[0] * v0[0] + v0[1] * v0[1] + v0[2] * v0[2] + v0[3] * v0[3];
    sq += v1[0] * v1[0] + v1[1] * v1[1] + v1[2] * v1[2] + v1[3] * v1[3];
    bf16x8 a = packbf8(v0, v1);
    #pragma unroll
    for (int t = 0; t < 4; ++t) {
      bf16x8 b = *(const bf16x8*)(pB + (size_t)t * 16 * 1024 + kk * 32);
      accY[t] = MFMA_B16(a, b, accY[t]);
    }
  }
  sq += __shfl_xor(sq, 16, 64);
  sq += __shfl_xor(sq, 32, 64);  // all lanes: ||H[row c16]||^2
  #pragma unroll
  for (int t = 0; t < 4; ++t)
    #pragma unroll
    for (int r = 0; r < 4; ++r)  // D: row = quad*4+reg, col = c16
      Yl[wid][quad * 4 + r][t * 16 + c16] = accY[t][r];
  __syncthreads();

  // ---- phase 2: C = Y @ W (Wb symmetric bf16, B read row-major) ----
  bf16x8 ya0 = cvt8(&Yl[wid][c16][quad * 8]);
  bf16x8 ya1 = cvt8(&Yl[wid][c16][32 + quad * 8]);
  f32x4 accC[4];
  #pragma unroll
  for (int t = 0; t < 4; ++t) accC[t] = (f32x4){0.f, 0.f, 0.f, 0.f};
  const unsigned short* wB = Wb + (size_t)c16 * 64 + quad * 8;
  #pragma unroll
  for (int t = 0; t < 4; ++t) {
    bf16x8 b0 = *(const bf16x8*)(wB + (size_t)t * 16 * 64);
    bf16x8 b1 = *(const bf16x8*)(wB + (size_t)t * 16 * 64 + 32);
    accC[t] = MFMA_B16(ya0, b0, accC[t]);
    accC[t] = MFMA_B16(ya1, b1, accC[t]);
  }
  #pragma unroll
  for (int t = 0; t < 4; ++t)
    #pragma unroll
    for (int r = 0; r < 4; ++r) Cl[wid][quad * 4 + r][t * 16 + c16] = accC[t][r];
  __syncthreads();

  // ---- per-row: dot = y.c = ||proj||^2 (row c16, r-range [quad*16, quad*16+16)) ----
  float d = 0.f;
  #pragma unroll
  for (int u = 0; u < 4; ++u) {
    f32x4 yv = *(const f32x4*)&Yl[wid][c16][quad * 16 + 4 * u];
    f32x4 cv = *(const f32x4*)&Cl[wid][c16][quad * 16 + 4 * u];
    d += yv[0] * cv[0] + yv[1] * cv[1] + yv[2] * cv[2] + yv[3] * cv[3];
  }
  d += __shfl_xor(d, 16, 64);
  d += __shfl_xor(d, 32, 64);
  const float scl = sqrtf(sq / fmaxf(sq - d, 1e-30f));  // scale for row c16

  // ---- phase 3: out = (H - C @ P^T) * scale; exact copy for s==0 rows ----
  bf16x8 ca0 = cvt8(&Cl[wid][c16][quad * 8]);
  bf16x8 ca1 = cvt8(&Cl[wid][c16][32 + quad * 8]);
  float sc[4]; long rg[4]; bool fs[4];
  #pragma unroll
  for (int r = 0; r < 4; ++r) {
    const int m = quad * 4 + r;
    sc[r] = __shfl(scl, m, 64);  // from lane m (c16==m)
    rg[r] = rowbase + m;
    fs[r] = ((rg[r] & 4095) == 0);
  }
  const unsigned short* pb3 = Pb + (size_t)c16 * 64 + quad * 8;
  #pragma unroll 2
  for (int ft = 0; ft < 64; ++ft) {
    bf16x8 b0 = *(const bf16x8*)(pb3 + (size_t)ft * 16 * 64);
    bf16x8 b1 = *(const bf16x8*)(pb3 + (size_t)ft * 16 * 64 + 32);
    f32x4 acc = (f32x4){0.f, 0.f, 0.f, 0.f};
    acc = MFMA_B16(ca0, b0, acc);
    acc = MFMA_B16(ca1, b1, acc);
    const int f = ft * 16 + c16;
    #pragma unroll
    for (int r = 0; r < 4; ++r) {
      const long idx = rg[r] * 1024 + f;
      const float h = H[idx];  // block-local re-read: L2/L3 hit
      const float o = fs[r] ? h : (h - acc[r]) * sc[r];
      __builtin_nontemporal_store(o, &out[idx]);
    }
  }
}

extern "C" void kernel_launch(void* const* d_in, const int* in_sizes, int n_in,
                              void* d_out, int out_size, void* d_ws, size_t ws_size,
                              hipStream_t stream) {
  const float* H = (const float*)d_in[0];  // 8*4096*1024 fp32
  const float* P = (const float*)d_in[1];  // 1024*64 fp32
  float* out = (float*)d_out;
  float* ws = (float*)d_ws;
  // ws: partial (16*4096 f32) | Ptb (65536 u16) | Pb (65536 u16) | Wb (4096 u16)
  float* partial = ws;
  unsigned short* Ptb = (unsigned short*)(ws + 16 * 4096);
  unsigned short* Pb = Ptb + 65536;
  unsigned short* Wb = Pb + 65536;

  pp_prep<<<16, 256, 0, stream>>>(P, partial, Ptb, Pb);
  pp_invert<<<1, 256, 0, stream>>>(partial, Wb);
  pp_main<<<512, 256, 0, stream>>>(H, Ptb, Pb, Wb, out);
}